// Round 9
// baseline (593.788 us; speedup 1.0000x reference)
//
#include <hip/hip_runtime.h>

typedef float  f32x4  __attribute__((ext_vector_type(4)));
typedef __bf16 bf16x8 __attribute__((ext_vector_type(8)));
typedef unsigned short u16x8 __attribute__((ext_vector_type(8)));
typedef unsigned short u16x4 __attribute__((ext_vector_type(4)));

#define DEV static __device__ __forceinline__

DEV unsigned short f2b(float f) {            // f32 -> bf16 (RNE)
  unsigned int u = __float_as_uint(f);
  u += 0x7fffu + ((u >> 16) & 1u);
  return (unsigned short)(u >> 16);
}
DEV float b2f(unsigned short h) { return __uint_as_float(((unsigned int)h) << 16); }

DEV f32x4 mfma16(bf16x8 a, bf16x8 b, f32x4 c) {
  return __builtin_amdgcn_mfma_f32_16x16x32_bf16(a, b, c, 0, 0, 0);
}

// ---------------------------------------------------------------- prep
__global__ __launch_bounds__(256) void k_prep(
    const float* __restrict__ Wq_comp, const float* __restrict__ Wkv_comp,
    const float* __restrict__ Wqc, const float* __restrict__ Wqr,
    const float* __restrict__ Wkc, const float* __restrict__ Wkr,
    const float* __restrict__ Wv,
    unsigned short* __restrict__ W1t, unsigned short* __restrict__ Wqt,
    unsigned short* __restrict__ Wkvt, float* __restrict__ ct, float* __restrict__ st) {
  int tid = blockIdx.x * 256 + threadIdx.x;
  if (tid < 131072) {                       // W1t
    int n = tid >> 8, k = tid & 255;
    float v = (n < 256) ? Wq_comp[k * 256 + n] : Wkv_comp[k * 256 + (n - 256)];
    W1t[tid] = f2b(v);
  } else if (tid < 196608) {                // Wqt
    int t2 = tid - 131072; int n = t2 >> 8, k = t2 & 255;
    float v = (n < 192) ? Wqc[k * 192 + n] : Wqr[k * 64 + (n - 192)];
    Wqt[t2] = f2b(v);
  } else if (tid < 327680) {                // Wkvt
    int t2 = tid - 196608; int n = t2 >> 8, k = t2 & 255;
    float v = (n < 192) ? Wkc[k * 192 + n]
             : (n < 256) ? Wkr[k * 64 + (n - 192)] : Wv[k * 256 + (n - 256)];
    Wkvt[t2] = f2b(v);
  } else if (tid < 393216) {                // rope table
    int t2 = tid - 327680; int t = t2 >> 5, i = t2 & 31;
    float theta = powf(10000.0f, -(float)i / 32.0f);
    float ang = (float)t * theta;
    ct[t2] = cosf(ang); st[t2] = sinf(ang);
  }
}

// ---------------------------------------------------------------- GEMM1: c_q/c_kv = x @ W1 (tile 128x256)
__global__ __launch_bounds__(512, 2) void k_gemm1(const float* __restrict__ X,
    const unsigned short* __restrict__ Bt, unsigned short* __restrict__ Cq,
    unsigned short* __restrict__ Ckv) {
  __shared__ __align__(16) unsigned short Ash[128 * 72];
  __shared__ __align__(16) unsigned short Bsh[256 * 72];
  const int nt2 = blockIdx.x, mt = blockIdx.y;
  const int tid = threadIdx.x;
  const int l = tid & 63, wv = tid >> 6, li = l & 15, g = l >> 4;
  const int wm = wv >> 2, wn = wv & 3;
  const f32x4 zf = {0.f, 0.f, 0.f, 0.f};
  f32x4 acc[4][4];
#pragma unroll
  for (int i = 0; i < 4; ++i)
#pragma unroll
    for (int j = 0; j < 4; ++j) acc[i][j] = zf;
  for (int kb = 0; kb < 256; kb += 64) {
    __syncthreads();
#pragma unroll
    for (int it = 0; it < 4; ++it) {        // A: 128x64 f32 -> bf16
      int idx = it * 512 + tid;
      int row = idx >> 4, c4 = (idx & 15) << 2;
      f32x4 v = *reinterpret_cast<const f32x4*>(X + (size_t)(mt * 128 + row) * 256 + kb + c4);
      u16x4 u = { f2b(v.x), f2b(v.y), f2b(v.z), f2b(v.w) };
      *reinterpret_cast<u16x4*>(&Ash[row * 72 + c4]) = u;
    }
#pragma unroll
    for (int it = 0; it < 4; ++it) {        // B: 256 rows of W1t
      int idx = it * 512 + tid;
      int row = idx >> 3, c8 = (idx & 7) << 3;
      *reinterpret_cast<u16x8*>(&Bsh[row * 72 + c8]) =
        *reinterpret_cast<const u16x8*>(Bt + (size_t)(nt2 * 256 + row) * 256 + kb + c8);
    }
    __syncthreads();
#pragma unroll
    for (int kc = 0; kc < 2; ++kc) {
      bf16x8 a[4], b[4];
#pragma unroll
      for (int mf = 0; mf < 4; ++mf)
        a[mf] = *reinterpret_cast<const bf16x8*>(&Ash[(wm * 64 + mf * 16 + li) * 72 + kc * 32 + g * 8]);
#pragma unroll
      for (int nf = 0; nf < 4; ++nf)
        b[nf] = *reinterpret_cast<const bf16x8*>(&Bsh[(wn * 64 + nf * 16 + li) * 72 + kc * 32 + g * 8]);
#pragma unroll
      for (int mf = 0; mf < 4; ++mf)
#pragma unroll
        for (int nf = 0; nf < 4; ++nf)
          acc[mf][nf] = mfma16(a[mf], b[nf], acc[mf][nf]);
    }
  }
  unsigned short* C = nt2 ? Ckv : Cq;
#pragma unroll
  for (int mf = 0; mf < 4; ++mf)
#pragma unroll
    for (int nf = 0; nf < 4; ++nf)
#pragma unroll
      for (int r = 0; r < 4; ++r) {
        int row = mt * 128 + wm * 64 + mf * 16 + g * 4 + r;
        int col = wn * 64 + nf * 16 + li;
        C[(size_t)row * 256 + col] = f2b(acc[mf][nf][r]);
      }
}

// ---------------------------------------------------------------- GEMM2: q/k/v projections (+RoPE, +vt transpose)
__global__ __launch_bounds__(512, 2) void k_gemm2(const unsigned short* __restrict__ Cq,
    const unsigned short* __restrict__ Ckv,
    const unsigned short* __restrict__ Wqt, const unsigned short* __restrict__ Wkvt,
    unsigned short* __restrict__ q_ws, unsigned short* __restrict__ k_ws,
    float* __restrict__ kout, float* __restrict__ vout,
    unsigned short* __restrict__ vt,
    const float* __restrict__ ct, const float* __restrict__ st, int sel0) {
  __shared__ __align__(16) unsigned short Ash[128 * 72];
  __shared__ __align__(16) unsigned short Bsh[256 * 72];
  const int sel = sel0 + blockIdx.x, mt = blockIdx.y;   // 0=q 1=k 2=v
  const int tid = threadIdx.x;
  const int l = tid & 63, wv = tid >> 6, li = l & 15, g = l >> 4;
  const int wm = wv >> 2, wn = wv & 3;
  const unsigned short* Asrc = (sel == 0) ? Cq : Ckv;
  const unsigned short* Wt = (sel == 0) ? Wqt : Wkvt;
  const int wrow = (sel == 2) ? 256 : 0;
  const f32x4 zf = {0.f, 0.f, 0.f, 0.f};
  f32x4 acc[4][4];
#pragma unroll
  for (int i = 0; i < 4; ++i)
#pragma unroll
    for (int j = 0; j < 4; ++j) acc[i][j] = zf;
  for (int kb = 0; kb < 256; kb += 64) {
    __syncthreads();
#pragma unroll
    for (int it = 0; it < 2; ++it) {        // A: 128x64 bf16
      int idx = it * 512 + tid;
      int row = idx >> 3, c8 = (idx & 7) << 3;
      *reinterpret_cast<u16x8*>(&Ash[row * 72 + c8]) =
        *reinterpret_cast<const u16x8*>(Asrc + (size_t)(mt * 128 + row) * 256 + kb + c8);
    }
#pragma unroll
    for (int it = 0; it < 4; ++it) {        // B: 256 rows
      int idx = it * 512 + tid;
      int row = idx >> 3, c8 = (idx & 7) << 3;
      *reinterpret_cast<u16x8*>(&Bsh[row * 72 + c8]) =
        *reinterpret_cast<const u16x8*>(Wt + (size_t)(wrow + row) * 256 + kb + c8);
    }
    __syncthreads();
#pragma unroll
    for (int kc = 0; kc < 2; ++kc) {
      bf16x8 a[4], b[4];
#pragma unroll
      for (int mf = 0; mf < 4; ++mf)
        a[mf] = *reinterpret_cast<const bf16x8*>(&Ash[(wm * 64 + mf * 16 + li) * 72 + kc * 32 + g * 8]);
#pragma unroll
      for (int nf = 0; nf < 4; ++nf)
        b[nf] = *reinterpret_cast<const bf16x8*>(&Bsh[(wn * 64 + nf * 16 + li) * 72 + kc * 32 + g * 8]);
#pragma unroll
      for (int mf = 0; mf < 4; ++mf)
#pragma unroll
        for (int nf = 0; nf < 4; ++nf)
          acc[mf][nf] = mfma16(a[mf], b[nf], acc[mf][nf]);
    }
  }
  // fused RoPE on local cols 192..255 (wn==3) for q (sel 0) and k (sel 1)
  if (sel < 2 && wn == 3) {
#pragma unroll
    for (int mf = 0; mf < 4; ++mf)
#pragma unroll
      for (int nf = 0; nf < 4; ++nf)
#pragma unroll
        for (int r = 0; r < 4; ++r) {
          float v = acc[mf][nf][r];
          float other = __shfl_xor(v, 1);
          int t = (mt * 128 + wm * 64 + mf * 16 + g * 4 + r) & 2047;
          int i = nf * 8 + (li >> 1);
          float c = ct[t * 32 + i], s = st[t * 32 + i];
          acc[mf][nf][r] = (li & 1) ? (other * s + v * c) : (v * c - other * s);
        }
  }
#pragma unroll
  for (int mf = 0; mf < 4; ++mf)
#pragma unroll
    for (int nf = 0; nf < 4; ++nf) {
      int cl = wn * 64 + nf * 16 + li;     // 0..255
#pragma unroll
      for (int r = 0; r < 4; ++r) {
        int row = mt * 128 + wm * 64 + mf * 16 + g * 4 + r;
        float val = acc[mf][nf][r];
        if (sel == 0) {
          q_ws[(size_t)row * 256 + cl] = f2b(val);
        } else if (sel == 1) {
          k_ws[(size_t)row * 256 + cl] = f2b(val);
          kout[(size_t)row * 256 + cl] = val;
        } else {
          vout[(size_t)row * 256 + cl] = val;
        }
      }
    }
  // sel==2: transposed bf16 write of this 128x256 tile into vt[b][d][t] via LDS bounce
  if (sel == 2) {
    const int batch = mt >> 4, tbase = (mt & 15) * 128;
#pragma unroll
    for (int h = 0; h < 2; ++h) {
      __syncthreads();
      if (wm == h) {
#pragma unroll
        for (int mf = 0; mf < 4; ++mf)
#pragma unroll
          for (int nf = 0; nf < 4; ++nf)
#pragma unroll
            for (int r = 0; r < 4; ++r) {
              int lr = mf * 16 + g * 4 + r;                  // 0..63
              int col = wn * 64 + nf * 16 + li;
              Bsh[lr * 258 + col] = f2b(acc[mf][nf][r]);
            }
      }
      __syncthreads();
#pragma unroll
      for (int it2 = 0; it2 < 8; ++it2) {
        int idx = it2 * 512 + tid;
        int d = idx >> 4, tq = (idx & 15) << 2;
        u16x4 pk = { Bsh[(tq + 0) * 258 + d], Bsh[(tq + 1) * 258 + d],
                     Bsh[(tq + 2) * 258 + d], Bsh[(tq + 3) * 258 + d] };
        *reinterpret_cast<u16x4*>(vt + ((size_t)batch * 256 + d) * 2048 + tbase + h * 64 + tq) = pk;
      }
    }
  }
}

// ---------------------------------------------------------------- flash attention v9
// R3's verified inner body (8 waves x 16 q-rows, Q-tile 128, KV-64, reg-staged
// double buffer), shrunk to 72KB LDS via 32-kv split-P -> 2 blocks/CU (16 waves).
// grid(32 b, 16 yy): qt perm -> co-resident pair (yy, yy+8) = 34 tiles/CU uniform;
// wgid%8 = b%8 -> XCD-pinned L2. Fixed-max softmax P = exp2(fma(s,C1,C2)), trunc pack.
__global__ __launch_bounds__(512, 4) void k_attn(
    const unsigned short* __restrict__ q_ws, const unsigned short* __restrict__ k_ws,
    const unsigned short* __restrict__ vt_ws, float* __restrict__ out) {
  __shared__ __align__(16) unsigned short Ksh[64 * 256];   // 32KB [kr][d] swizzled
  __shared__ __align__(16) unsigned short Vsh[256 * 64];   // 32KB [d][kk] swizzled
  __shared__ __align__(16) unsigned short Psh[8][512];     // 8KB per-wave [16 q][32 kk] half
  const int b = blockIdx.x;
  const int yy = blockIdx.y;
  const int qt = (yy < 8) ? (15 - 2 * yy) : (2 * (yy - 8));
  const int tid = threadIdx.x;
  const int l = tid & 63, wv = tid >> 6, li = l & 15, g = l >> 4;
  const f32x4 zf = {0.f, 0.f, 0.f, 0.f};
  const float C1 = 0.09016844005556021f;    // log2(e)/16
  const float C2 = -11.541560327111707f;    // -8*log2(e)

  u16x8 ones_u = {0x3F80, 0x3F80, 0x3F80, 0x3F80, 0x3F80, 0x3F80, 0x3F80, 0x3F80};
  bf16x8 ones = *reinterpret_cast<bf16x8*>(&ones_u);

  const unsigned short* kbase = k_ws + (size_t)b * 2048 * 256;
  const unsigned short* vbase = vt_ws + (size_t)b * 256 * 2048;

  u16x8 kreg[4], vreg[4];
  // K: chunk = rnd*512+tid -> row=chunk>>5 (0..63), pc=chunk&31.
  // V: chunk = rnd*512+tid -> d=chunk>>3 (0..255), pc=chunk&7.
#define LOADREGS(t)                                                                   \
  {                                                                                   \
    const unsigned short* ks_ = kbase + (size_t)(t) * 64 * 256;                       \
    const unsigned short* vs_ = vbase + (size_t)(t) * 64;                             \
    _Pragma("unroll")                                                                 \
    for (int rnd = 0; rnd < 4; ++rnd) {                                               \
      int chunk = rnd * 512 + tid;                                                    \
      kreg[rnd] = *reinterpret_cast<const u16x8*>(ks_ + (size_t)(chunk >> 5) * 256 + (chunk & 31) * 8); \
    }                                                                                 \
    _Pragma("unroll")                                                                 \
    for (int rnd = 0; rnd < 4; ++rnd) {                                               \
      int chunk = rnd * 512 + tid;                                                    \
      vreg[rnd] = *reinterpret_cast<const u16x8*>(vs_ + (size_t)(chunk >> 3) * 2048 + (chunk & 7) * 8); \
    }                                                                                 \
  }

  const int wq0 = qt * 128 + wv * 16;       // this wave's first q row
  bf16x8 qf[8];
  const unsigned short* qp = q_ws + ((size_t)b * 2048 + wq0 + li) * 256;
#pragma unroll
  for (int kc = 0; kc < 8; ++kc)
    qf[kc] = *reinterpret_cast<const bf16x8*>(qp + kc * 32 + g * 8);

  f32x4 o[16];
#pragma unroll
  for (int i = 0; i < 16; ++i) o[i] = zf;
  f32x4 ol = zf;

  const int nj = 2 * qt + 2;                // KV-64 tiles
  LOADREGS(0);

  for (int j = 0; j < nj; ++j) {
    __syncthreads();                        // previous iteration's readers done
#pragma unroll
    for (int rnd = 0; rnd < 4; ++rnd) {     // K regs -> LDS (swizzled)
      int chunk = rnd * 512 + tid;
      int row = chunk >> 5, pc = chunk & 31;
      *reinterpret_cast<u16x8*>(&Ksh[row * 256 + (pc ^ (row & 7)) * 8]) = kreg[rnd];
    }
#pragma unroll
    for (int rnd = 0; rnd < 4; ++rnd) {     // V regs -> LDS (swizzled)
      int chunk = rnd * 512 + tid;
      int d = chunk >> 3, pc = chunk & 7;
      *reinterpret_cast<u16x8*>(&Vsh[d * 64 + (pc ^ (d & 7)) * 8]) = vreg[rnd];
    }
    __syncthreads();
    if (j + 1 < nj) LOADREGS(j + 1);        // prefetch next tile into regs

    if (j * 64 <= wq0 + 15) {               // wave has unmasked work this tile
      // QK^T: 16 q rows x 64 k rows
      f32x4 s[4];
#pragma unroll
      for (int nf = 0; nf < 4; ++nf) s[nf] = zf;
#pragma unroll
      for (int kc = 0; kc < 8; ++kc) {
        int pc = (kc * 4 + g) ^ (li & 7);
#pragma unroll
        for (int nf = 0; nf < 4; ++nf) {
          bf16x8 bk = *reinterpret_cast<const bf16x8*>(&Ksh[(nf * 16 + li) * 256 + pc * 8]);
          s[nf] = mfma16(qf[kc], bk, s[nf]);
        }
      }
      const bool needmask = (j * 64 + 63) > wq0;
      // softmax numerator + PV in two 32-kv halves (split-P: 1KB/wave)
#pragma unroll
      for (int h = 0; h < 2; ++h) {
#pragma unroll
        for (int r = 0; r < 4; ++r) {
          const int q = g * 4 + r;          // local row 0..15
          const int sw = (q & 3) ^ (q >> 2);
#pragma unroll
          for (int nf2 = 0; nf2 < 2; ++nf2) {
            const int nf = h * 2 + nf2;
            float pv = __builtin_amdgcn_exp2f(__builtin_fmaf(s[nf][r], C1, C2));
            if (needmask) {
              int kg = j * 64 + nf * 16 + li;
              if (kg > wq0 + q) pv = 0.f;
            }
            int kkl = nf2 * 16 + li;        // 0..31 within half
            Psh[wv][q * 32 + (((kkl >> 3) ^ sw) << 3) + (kkl & 7)] =
                (unsigned short)(__float_as_uint(pv) >> 16);
          }
        }
        // read P A-frag: row li, kv-chunk g stored at slot g ^ (li&3) ^ (li>>2)
        bf16x8 pa = *reinterpret_cast<const bf16x8*>(
            &Psh[wv][li * 32 + ((g ^ (li & 3) ^ (li >> 2)) << 3)]);
        ol = mfma16(pa, ones, ol);
        const int cb = h * 4 + g;           // global kv chunk 0..7
#pragma unroll
        for (int nfd = 0; nfd < 16; ++nfd) {
          int d = nfd * 16 + li;
          bf16x8 bv = *reinterpret_cast<const bf16x8*>(&Vsh[d * 64 + (cb ^ (d & 7)) * 8]);
          o[nfd] = mfma16(pa, bv, o[nfd]);
        }
      }
    }
  }

  // epilogue: 16 rows x 256 cols
#pragma unroll
  for (int r = 0; r < 4; ++r) {
    float inv = 1.0f / ol[r];
    int qrow = wq0 + g * 4 + r;
    float* op = out + ((size_t)b * 2048 + qrow) * 256;
#pragma unroll
    for (int nfd = 0; nfd < 16; ++nfd)
      op[nfd * 16 + li] = o[nfd][r] * inv;
  }
#undef LOADREGS
}

// ---------------------------------------------------------------- launch
extern "C" void kernel_launch(void* const* d_in, const int* in_sizes, int n_in,
                              void* d_out, int out_size, void* d_ws, size_t ws_size,
                              hipStream_t stream) {
  const float* x        = (const float*)d_in[0];
  const float* Wq_comp  = (const float*)d_in[1];
  const float* Wkv_comp = (const float*)d_in[2];
  const float* Wqc      = (const float*)d_in[3];
  const float* Wqr      = (const float*)d_in[4];
  const float* Wkc      = (const float*)d_in[5];
  const float* Wkr      = (const float*)d_in[6];
  const float* Wv       = (const float*)d_in[7];

  float* out  = (float*)d_out;            // [32][2048][256]
  float* kout = out + 16777216;           // k output (f32)
  float* vout = out + 33554432;           // v output (f32)

  if (ws_size < 135397376u) return;

  char* ws = (char*)d_ws;
  unsigned short* c_q  = (unsigned short*)(ws);              // 32MB (vt aliases after q done)
  unsigned short* vt   = (unsigned short*)(ws);              // [32][256][2048] bf16 (32MB)
  unsigned short* c_kv = (unsigned short*)(ws + 33554432);   // 32MB
  unsigned short* q_ws = (unsigned short*)(ws + 67108864);   // 32MB
  unsigned short* k_ws = (unsigned short*)(ws + 100663296);  // 32MB
  unsigned short* W1t  = (unsigned short*)(ws + 134217728);  // 512x256
  unsigned short* Wqt  = W1t + 131072;                       // 256x256
  unsigned short* Wkvt = Wqt + 65536;                        // 512x256
  float* ct = (float*)(Wkvt + 131072);                       // 2048x32
  float* st = ct + 65536;

  k_prep<<<1536, 256, 0, stream>>>(Wq_comp, Wkv_comp, Wqc, Wqr, Wkc, Wkr, Wv,
                                   W1t, Wqt, Wkvt, ct, st);
  k_gemm1<<<dim3(2, 512), 512, 0, stream>>>(x, W1t, c_q, c_kv);
  // q and k first (read c_q/c_kv); then v (reads only c_kv, writes vt over c_q)
  k_gemm2<<<dim3(2, 512), 512, 0, stream>>>(c_q, c_kv, Wqt, Wkvt, q_ws, k_ws,
                                            kout, vout, vt, ct, st, 0);
  k_gemm2<<<dim3(1, 512), 512, 0, stream>>>(c_q, c_kv, Wqt, Wkvt, q_ws, k_ws,
                                            kout, vout, vt, ct, st, 2);
  k_attn<<<dim3(32, 16), 512, 0, stream>>>(q_ws, k_ws, vt, out);
}

// Round 10
// 307.845 us; speedup vs baseline: 1.9288x; 1.9288x over previous
//
#include <hip/hip_runtime.h>

typedef float  f32x4  __attribute__((ext_vector_type(4)));
typedef __bf16 bf16x8 __attribute__((ext_vector_type(8)));
typedef unsigned short u16x8 __attribute__((ext_vector_type(8)));
typedef unsigned short u16x4 __attribute__((ext_vector_type(4)));

#define DEV static __device__ __forceinline__

DEV unsigned short f2b(float f) {            // f32 -> bf16 (RNE)
  unsigned int u = __float_as_uint(f);
  u += 0x7fffu + ((u >> 16) & 1u);
  return (unsigned short)(u >> 16);
}
DEV float b2f(unsigned short h) { return __uint_as_float(((unsigned int)h) << 16); }

DEV f32x4 mfma16(bf16x8 a, bf16x8 b, f32x4 c) {
  return __builtin_amdgcn_mfma_f32_16x16x32_bf16(a, b, c, 0, 0, 0);
}

// ---------------------------------------------------------------- prep
__global__ __launch_bounds__(256) void k_prep(
    const float* __restrict__ Wq_comp, const float* __restrict__ Wkv_comp,
    const float* __restrict__ Wqc, const float* __restrict__ Wqr,
    const float* __restrict__ Wkc, const float* __restrict__ Wkr,
    const float* __restrict__ Wv,
    unsigned short* __restrict__ W1t, unsigned short* __restrict__ Wqt,
    unsigned short* __restrict__ Wkvt, float* __restrict__ ct, float* __restrict__ st) {
  int tid = blockIdx.x * 256 + threadIdx.x;
  if (tid < 131072) {                       // W1t
    int n = tid >> 8, k = tid & 255;
    float v = (n < 256) ? Wq_comp[k * 256 + n] : Wkv_comp[k * 256 + (n - 256)];
    W1t[tid] = f2b(v);
  } else if (tid < 196608) {                // Wqt
    int t2 = tid - 131072; int n = t2 >> 8, k = t2 & 255;
    float v = (n < 192) ? Wqc[k * 192 + n] : Wqr[k * 64 + (n - 192)];
    Wqt[t2] = f2b(v);
  } else if (tid < 327680) {                // Wkvt
    int t2 = tid - 196608; int n = t2 >> 8, k = t2 & 255;
    float v = (n < 192) ? Wkc[k * 192 + n]
             : (n < 256) ? Wkr[k * 64 + (n - 192)] : Wv[k * 256 + (n - 256)];
    Wkvt[t2] = f2b(v);
  } else if (tid < 393216) {                // rope table
    int t2 = tid - 327680; int t = t2 >> 5, i = t2 & 31;
    float theta = powf(10000.0f, -(float)i / 32.0f);
    float ang = (float)t * theta;
    ct[t2] = cosf(ang); st[t2] = sinf(ang);
  }
}

// ---------------------------------------------------------------- GEMM1: c_q/c_kv = x @ W1 (tile 128x256)
__global__ __launch_bounds__(512, 2) void k_gemm1(const float* __restrict__ X,
    const unsigned short* __restrict__ Bt, unsigned short* __restrict__ Cq,
    unsigned short* __restrict__ Ckv) {
  __shared__ __align__(16) unsigned short Ash[128 * 72];
  __shared__ __align__(16) unsigned short Bsh[256 * 72];
  const int nt2 = blockIdx.x, mt = blockIdx.y;
  const int tid = threadIdx.x;
  const int l = tid & 63, wv = tid >> 6, li = l & 15, g = l >> 4;
  const int wm = wv >> 2, wn = wv & 3;
  const f32x4 zf = {0.f, 0.f, 0.f, 0.f};
  f32x4 acc[4][4];
#pragma unroll
  for (int i = 0; i < 4; ++i)
#pragma unroll
    for (int j = 0; j < 4; ++j) acc[i][j] = zf;
  for (int kb = 0; kb < 256; kb += 64) {
    __syncthreads();
#pragma unroll
    for (int it = 0; it < 4; ++it) {        // A: 128x64 f32 -> bf16
      int idx = it * 512 + tid;
      int row = idx >> 4, c4 = (idx & 15) << 2;
      f32x4 v = *reinterpret_cast<const f32x4*>(X + (size_t)(mt * 128 + row) * 256 + kb + c4);
      u16x4 u = { f2b(v.x), f2b(v.y), f2b(v.z), f2b(v.w) };
      *reinterpret_cast<u16x4*>(&Ash[row * 72 + c4]) = u;
    }
#pragma unroll
    for (int it = 0; it < 4; ++it) {        // B: 256 rows of W1t
      int idx = it * 512 + tid;
      int row = idx >> 3, c8 = (idx & 7) << 3;
      *reinterpret_cast<u16x8*>(&Bsh[row * 72 + c8]) =
        *reinterpret_cast<const u16x8*>(Bt + (size_t)(nt2 * 256 + row) * 256 + kb + c8);
    }
    __syncthreads();
#pragma unroll
    for (int kc = 0; kc < 2; ++kc) {
      bf16x8 a[4], b[4];
#pragma unroll
      for (int mf = 0; mf < 4; ++mf)
        a[mf] = *reinterpret_cast<const bf16x8*>(&Ash[(wm * 64 + mf * 16 + li) * 72 + kc * 32 + g * 8]);
#pragma unroll
      for (int nf = 0; nf < 4; ++nf)
        b[nf] = *reinterpret_cast<const bf16x8*>(&Bsh[(wn * 64 + nf * 16 + li) * 72 + kc * 32 + g * 8]);
#pragma unroll
      for (int mf = 0; mf < 4; ++mf)
#pragma unroll
        for (int nf = 0; nf < 4; ++nf)
          acc[mf][nf] = mfma16(a[mf], b[nf], acc[mf][nf]);
    }
  }
  unsigned short* C = nt2 ? Ckv : Cq;
#pragma unroll
  for (int mf = 0; mf < 4; ++mf)
#pragma unroll
    for (int nf = 0; nf < 4; ++nf)
#pragma unroll
      for (int r = 0; r < 4; ++r) {
        int row = mt * 128 + wm * 64 + mf * 16 + g * 4 + r;
        int col = wn * 64 + nf * 16 + li;
        C[(size_t)row * 256 + col] = f2b(acc[mf][nf][r]);
      }
}

// ---------------------------------------------------------------- GEMM2: q/k/v projections (+RoPE, +vt transpose)
__global__ __launch_bounds__(512, 2) void k_gemm2(const unsigned short* __restrict__ Cq,
    const unsigned short* __restrict__ Ckv,
    const unsigned short* __restrict__ Wqt, const unsigned short* __restrict__ Wkvt,
    unsigned short* __restrict__ q_ws, unsigned short* __restrict__ k_ws,
    float* __restrict__ kout, float* __restrict__ vout,
    unsigned short* __restrict__ vt,
    const float* __restrict__ ct, const float* __restrict__ st, int sel0) {
  __shared__ __align__(16) unsigned short Ash[128 * 72];
  __shared__ __align__(16) unsigned short Bsh[256 * 72];
  const int sel = sel0 + blockIdx.x, mt = blockIdx.y;   // 0=q 1=k 2=v
  const int tid = threadIdx.x;
  const int l = tid & 63, wv = tid >> 6, li = l & 15, g = l >> 4;
  const int wm = wv >> 2, wn = wv & 3;
  const unsigned short* Asrc = (sel == 0) ? Cq : Ckv;
  const unsigned short* Wt = (sel == 0) ? Wqt : Wkvt;
  const int wrow = (sel == 2) ? 256 : 0;
  const f32x4 zf = {0.f, 0.f, 0.f, 0.f};
  f32x4 acc[4][4];
#pragma unroll
  for (int i = 0; i < 4; ++i)
#pragma unroll
    for (int j = 0; j < 4; ++j) acc[i][j] = zf;
  for (int kb = 0; kb < 256; kb += 64) {
    __syncthreads();
#pragma unroll
    for (int it = 0; it < 2; ++it) {        // A: 128x64 bf16
      int idx = it * 512 + tid;
      int row = idx >> 3, c8 = (idx & 7) << 3;
      *reinterpret_cast<u16x8*>(&Ash[row * 72 + c8]) =
        *reinterpret_cast<const u16x8*>(Asrc + (size_t)(mt * 128 + row) * 256 + kb + c8);
    }
#pragma unroll
    for (int it = 0; it < 4; ++it) {        // B: 256 rows
      int idx = it * 512 + tid;
      int row = idx >> 3, c8 = (idx & 7) << 3;
      *reinterpret_cast<u16x8*>(&Bsh[row * 72 + c8]) =
        *reinterpret_cast<const u16x8*>(Wt + (size_t)(wrow + row) * 256 + kb + c8);
    }
    __syncthreads();
#pragma unroll
    for (int kc = 0; kc < 2; ++kc) {
      bf16x8 a[4], b[4];
#pragma unroll
      for (int mf = 0; mf < 4; ++mf)
        a[mf] = *reinterpret_cast<const bf16x8*>(&Ash[(wm * 64 + mf * 16 + li) * 72 + kc * 32 + g * 8]);
#pragma unroll
      for (int nf = 0; nf < 4; ++nf)
        b[nf] = *reinterpret_cast<const bf16x8*>(&Bsh[(wn * 64 + nf * 16 + li) * 72 + kc * 32 + g * 8]);
#pragma unroll
      for (int mf = 0; mf < 4; ++mf)
#pragma unroll
        for (int nf = 0; nf < 4; ++nf)
          acc[mf][nf] = mfma16(a[mf], b[nf], acc[mf][nf]);
    }
  }
  // fused RoPE on local cols 192..255 (wn==3) for q (sel 0) and k (sel 1)
  if (sel < 2 && wn == 3) {
#pragma unroll
    for (int mf = 0; mf < 4; ++mf)
#pragma unroll
      for (int nf = 0; nf < 4; ++nf)
#pragma unroll
        for (int r = 0; r < 4; ++r) {
          float v = acc[mf][nf][r];
          float other = __shfl_xor(v, 1);
          int t = (mt * 128 + wm * 64 + mf * 16 + g * 4 + r) & 2047;
          int i = nf * 8 + (li >> 1);
          float c = ct[t * 32 + i], s = st[t * 32 + i];
          acc[mf][nf][r] = (li & 1) ? (other * s + v * c) : (v * c - other * s);
        }
  }
#pragma unroll
  for (int mf = 0; mf < 4; ++mf)
#pragma unroll
    for (int nf = 0; nf < 4; ++nf) {
      int cl = wn * 64 + nf * 16 + li;     // 0..255
#pragma unroll
      for (int r = 0; r < 4; ++r) {
        int row = mt * 128 + wm * 64 + mf * 16 + g * 4 + r;
        float val = acc[mf][nf][r];
        if (sel == 0) {
          q_ws[(size_t)row * 256 + cl] = f2b(val);
        } else if (sel == 1) {
          k_ws[(size_t)row * 256 + cl] = f2b(val);
          kout[(size_t)row * 256 + cl] = val;
        } else {
          vout[(size_t)row * 256 + cl] = val;
        }
      }
    }
  // sel==2: transposed bf16 write of this 128x256 tile into vt[b][d][t] via LDS bounce
  if (sel == 2) {
    const int batch = mt >> 4, tbase = (mt & 15) * 128;
#pragma unroll
    for (int h = 0; h < 2; ++h) {
      __syncthreads();
      if (wm == h) {
#pragma unroll
        for (int mf = 0; mf < 4; ++mf)
#pragma unroll
          for (int nf = 0; nf < 4; ++nf)
#pragma unroll
            for (int r = 0; r < 4; ++r) {
              int lr = mf * 16 + g * 4 + r;                  // 0..63
              int col = wn * 64 + nf * 16 + li;
              Bsh[lr * 258 + col] = f2b(acc[mf][nf][r]);
            }
      }
      __syncthreads();
#pragma unroll
      for (int it2 = 0; it2 < 8; ++it2) {
        int idx = it2 * 512 + tid;
        int d = idx >> 4, tq = (idx & 15) << 2;
        u16x4 pk = { Bsh[(tq + 0) * 258 + d], Bsh[(tq + 1) * 258 + d],
                     Bsh[(tq + 2) * 258 + d], Bsh[(tq + 3) * 258 + d] };
        *reinterpret_cast<u16x4*>(vt + ((size_t)batch * 256 + d) * 2048 + tbase + h * 64 + tq) = pk;
      }
    }
  }
}

// ---------------------------------------------------------------- flash attention v10 (= R9 structure, correct launch bounds)
// 8 waves x 16 q-rows, Q-tile 128, KV-64, reg-staged double buffer; 72KB LDS
// (32-kv split-P) -> 2 blocks/CU. __launch_bounds__(512,2): 2 BLOCKS/CU min
// (HIP arg = blocks, not waves!) -> VGPR cap 128, no spill (R3 body = 116).
// grid(32 b, 16 yy): qt perm -> co-resident pair (yy, yy+8) = 34 tiles/CU uniform;
// wgid%8 = b%8 -> XCD-pinned L2. Fixed-max softmax P = exp2(fma(s,C1,C2)), trunc pack.
__global__ __launch_bounds__(512, 2) void k_attn(
    const unsigned short* __restrict__ q_ws, const unsigned short* __restrict__ k_ws,
    const unsigned short* __restrict__ vt_ws, float* __restrict__ out) {
  __shared__ __align__(16) unsigned short Ksh[64 * 256];   // 32KB [kr][d] swizzled
  __shared__ __align__(16) unsigned short Vsh[256 * 64];   // 32KB [d][kk] swizzled
  __shared__ __align__(16) unsigned short Psh[8][512];     // 8KB per-wave [16 q][32 kk] half
  const int b = blockIdx.x;
  const int yy = blockIdx.y;
  const int qt = (yy < 8) ? (15 - 2 * yy) : (2 * (yy - 8));
  const int tid = threadIdx.x;
  const int l = tid & 63, wv = tid >> 6, li = l & 15, g = l >> 4;
  const f32x4 zf = {0.f, 0.f, 0.f, 0.f};
  const float C1 = 0.09016844005556021f;    // log2(e)/16
  const float C2 = -11.541560327111707f;    // -8*log2(e)

  u16x8 ones_u = {0x3F80, 0x3F80, 0x3F80, 0x3F80, 0x3F80, 0x3F80, 0x3F80, 0x3F80};
  bf16x8 ones = *reinterpret_cast<bf16x8*>(&ones_u);

  const unsigned short* kbase = k_ws + (size_t)b * 2048 * 256;
  const unsigned short* vbase = vt_ws + (size_t)b * 256 * 2048;

  u16x8 kreg[4], vreg[4];
  // K: chunk = rnd*512+tid -> row=chunk>>5 (0..63), pc=chunk&31.
  // V: chunk = rnd*512+tid -> d=chunk>>3 (0..255), pc=chunk&7.
#define LOADREGS(t)                                                                   \
  {                                                                                   \
    const unsigned short* ks_ = kbase + (size_t)(t) * 64 * 256;                       \
    const unsigned short* vs_ = vbase + (size_t)(t) * 64;                             \
    _Pragma("unroll")                                                                 \
    for (int rnd = 0; rnd < 4; ++rnd) {                                               \
      int chunk = rnd * 512 + tid;                                                    \
      kreg[rnd] = *reinterpret_cast<const u16x8*>(ks_ + (size_t)(chunk >> 5) * 256 + (chunk & 31) * 8); \
    }                                                                                 \
    _Pragma("unroll")                                                                 \
    for (int rnd = 0; rnd < 4; ++rnd) {                                               \
      int chunk = rnd * 512 + tid;                                                    \
      vreg[rnd] = *reinterpret_cast<const u16x8*>(vs_ + (size_t)(chunk >> 3) * 2048 + (chunk & 7) * 8); \
    }                                                                                 \
  }

  const int wq0 = qt * 128 + wv * 16;       // this wave's first q row
  bf16x8 qf[8];
  const unsigned short* qp = q_ws + ((size_t)b * 2048 + wq0 + li) * 256;
#pragma unroll
  for (int kc = 0; kc < 8; ++kc)
    qf[kc] = *reinterpret_cast<const bf16x8*>(qp + kc * 32 + g * 8);

  f32x4 o[16];
#pragma unroll
  for (int i = 0; i < 16; ++i) o[i] = zf;
  f32x4 ol = zf;

  const int nj = 2 * qt + 2;                // KV-64 tiles
  LOADREGS(0);

  for (int j = 0; j < nj; ++j) {
    __syncthreads();                        // previous iteration's readers done
#pragma unroll
    for (int rnd = 0; rnd < 4; ++rnd) {     // K regs -> LDS (swizzled)
      int chunk = rnd * 512 + tid;
      int row = chunk >> 5, pc = chunk & 31;
      *reinterpret_cast<u16x8*>(&Ksh[row * 256 + (pc ^ (row & 7)) * 8]) = kreg[rnd];
    }
#pragma unroll
    for (int rnd = 0; rnd < 4; ++rnd) {     // V regs -> LDS (swizzled)
      int chunk = rnd * 512 + tid;
      int d = chunk >> 3, pc = chunk & 7;
      *reinterpret_cast<u16x8*>(&Vsh[d * 64 + (pc ^ (d & 7)) * 8]) = vreg[rnd];
    }
    __syncthreads();
    if (j + 1 < nj) LOADREGS(j + 1);        // prefetch next tile into regs

    if (j * 64 <= wq0 + 15) {               // wave has unmasked work this tile
      // QK^T: 16 q rows x 64 k rows
      f32x4 s[4];
#pragma unroll
      for (int nf = 0; nf < 4; ++nf) s[nf] = zf;
#pragma unroll
      for (int kc = 0; kc < 8; ++kc) {
        int pc = (kc * 4 + g) ^ (li & 7);
#pragma unroll
        for (int nf = 0; nf < 4; ++nf) {
          bf16x8 bk = *reinterpret_cast<const bf16x8*>(&Ksh[(nf * 16 + li) * 256 + pc * 8]);
          s[nf] = mfma16(qf[kc], bk, s[nf]);
        }
      }
      const bool needmask = (j * 64 + 63) > wq0;
      // softmax numerator + PV in two 32-kv halves (split-P: 1KB/wave)
#pragma unroll
      for (int h = 0; h < 2; ++h) {
#pragma unroll
        for (int r = 0; r < 4; ++r) {
          const int q = g * 4 + r;          // local row 0..15
          const int sw = (q & 3) ^ (q >> 2);
#pragma unroll
          for (int nf2 = 0; nf2 < 2; ++nf2) {
            const int nf = h * 2 + nf2;
            float pv = __builtin_amdgcn_exp2f(__builtin_fmaf(s[nf][r], C1, C2));
            if (needmask) {
              int kg = j * 64 + nf * 16 + li;
              if (kg > wq0 + q) pv = 0.f;
            }
            int kkl = nf2 * 16 + li;        // 0..31 within half
            Psh[wv][q * 32 + (((kkl >> 3) ^ sw) << 3) + (kkl & 7)] =
                (unsigned short)(__float_as_uint(pv) >> 16);
          }
        }
        // read P A-frag: row li, kv-chunk g stored at slot g ^ (li&3) ^ (li>>2)
        bf16x8 pa = *reinterpret_cast<const bf16x8*>(
            &Psh[wv][li * 32 + ((g ^ (li & 3) ^ (li >> 2)) << 3)]);
        ol = mfma16(pa, ones, ol);
        const int cb = h * 4 + g;           // global kv chunk 0..7
#pragma unroll
        for (int nfd = 0; nfd < 16; ++nfd) {
          int d = nfd * 16 + li;
          bf16x8 bv = *reinterpret_cast<const bf16x8*>(&Vsh[d * 64 + (cb ^ (d & 7)) * 8]);
          o[nfd] = mfma16(pa, bv, o[nfd]);
        }
      }
    }
  }

  // epilogue: 16 rows x 256 cols
#pragma unroll
  for (int r = 0; r < 4; ++r) {
    float inv = 1.0f / ol[r];
    int qrow = wq0 + g * 4 + r;
    float* op = out + ((size_t)b * 2048 + qrow) * 256;
#pragma unroll
    for (int nfd = 0; nfd < 16; ++nfd)
      op[nfd * 16 + li] = o[nfd][r] * inv;
  }
#undef LOADREGS
}

// ---------------------------------------------------------------- launch
extern "C" void kernel_launch(void* const* d_in, const int* in_sizes, int n_in,
                              void* d_out, int out_size, void* d_ws, size_t ws_size,
                              hipStream_t stream) {
  const float* x        = (const float*)d_in[0];
  const float* Wq_comp  = (const float*)d_in[1];
  const float* Wkv_comp = (const float*)d_in[2];
  const float* Wqc      = (const float*)d_in[3];
  const float* Wqr      = (const float*)d_in[4];
  const float* Wkc      = (const float*)d_in[5];
  const float* Wkr      = (const float*)d_in[6];
  const float* Wv       = (const float*)d_in[7];

  float* out  = (float*)d_out;            // [32][2048][256]
  float* kout = out + 16777216;           // k output (f32)
  float* vout = out + 33554432;           // v output (f32)

  if (ws_size < 135397376u) return;

  char* ws = (char*)d_ws;
  unsigned short* c_q  = (unsigned short*)(ws);              // 32MB (vt aliases after q done)
  unsigned short* vt   = (unsigned short*)(ws);              // [32][256][2048] bf16 (32MB)
  unsigned short* c_kv = (unsigned short*)(ws + 33554432);   // 32MB
  unsigned short* q_ws = (unsigned short*)(ws + 67108864);   // 32MB
  unsigned short* k_ws = (unsigned short*)(ws + 100663296);  // 32MB
  unsigned short* W1t  = (unsigned short*)(ws + 134217728);  // 512x256
  unsigned short* Wqt  = W1t + 131072;                       // 256x256
  unsigned short* Wkvt = Wqt + 65536;                        // 512x256
  float* ct = (float*)(Wkvt + 131072);                       // 2048x32
  float* st = ct + 65536;

  k_prep<<<1536, 256, 0, stream>>>(Wq_comp, Wkv_comp, Wqc, Wqr, Wkc, Wkr, Wv,
                                   W1t, Wqt, Wkvt, ct, st);
  k_gemm1<<<dim3(2, 512), 512, 0, stream>>>(x, W1t, c_q, c_kv);
  // q and k first (read c_q/c_kv); then v (reads only c_kv, writes vt over c_q)
  k_gemm2<<<dim3(2, 512), 512, 0, stream>>>(c_q, c_kv, Wqt, Wkvt, q_ws, k_ws,
                                            kout, vout, vt, ct, st, 0);
  k_gemm2<<<dim3(1, 512), 512, 0, stream>>>(c_q, c_kv, Wqt, Wkvt, q_ws, k_ws,
                                            kout, vout, vt, ct, st, 2);
  k_attn<<<dim3(32, 16), 512, 0, stream>>>(q_ws, k_ws, vt, out);
}

// Round 11
// 263.541 us; speedup vs baseline: 2.2531x; 1.1681x over previous
//
#include <hip/hip_runtime.h>

typedef float  f32x4  __attribute__((ext_vector_type(4)));
typedef __bf16 bf16x8 __attribute__((ext_vector_type(8)));
typedef unsigned short u16x8 __attribute__((ext_vector_type(8)));
typedef unsigned short u16x4 __attribute__((ext_vector_type(4)));

#define DEV static __device__ __forceinline__

DEV unsigned short f2b(float f) {            // f32 -> bf16 (RNE)
  unsigned int u = __float_as_uint(f);
  u += 0x7fffu + ((u >> 16) & 1u);
  return (unsigned short)(u >> 16);
}
DEV float b2f(unsigned short h) { return __uint_as_float(((unsigned int)h) << 16); }

DEV f32x4 mfma16(bf16x8 a, bf16x8 b, f32x4 c) {
  return __builtin_amdgcn_mfma_f32_16x16x32_bf16(a, b, c, 0, 0, 0);
}

// ---------------------------------------------------------------- prep
__global__ __launch_bounds__(256) void k_prep(
    const float* __restrict__ Wq_comp, const float* __restrict__ Wkv_comp,
    const float* __restrict__ Wqc, const float* __restrict__ Wqr,
    const float* __restrict__ Wkc, const float* __restrict__ Wkr,
    const float* __restrict__ Wv,
    unsigned short* __restrict__ W1t, unsigned short* __restrict__ Wqt,
    unsigned short* __restrict__ Wkvt, float* __restrict__ ct, float* __restrict__ st) {
  int tid = blockIdx.x * 256 + threadIdx.x;
  if (tid < 131072) {                       // W1t
    int n = tid >> 8, k = tid & 255;
    float v = (n < 256) ? Wq_comp[k * 256 + n] : Wkv_comp[k * 256 + (n - 256)];
    W1t[tid] = f2b(v);
  } else if (tid < 196608) {                // Wqt
    int t2 = tid - 131072; int n = t2 >> 8, k = t2 & 255;
    float v = (n < 192) ? Wqc[k * 192 + n] : Wqr[k * 64 + (n - 192)];
    Wqt[t2] = f2b(v);
  } else if (tid < 327680) {                // Wkvt
    int t2 = tid - 196608; int n = t2 >> 8, k = t2 & 255;
    float v = (n < 192) ? Wkc[k * 192 + n]
             : (n < 256) ? Wkr[k * 64 + (n - 192)] : Wv[k * 256 + (n - 256)];
    Wkvt[t2] = f2b(v);
  } else if (tid < 393216) {                // rope table
    int t2 = tid - 327680; int t = t2 >> 5, i = t2 & 31;
    float theta = powf(10000.0f, -(float)i / 32.0f);
    float ang = (float)t * theta;
    ct[t2] = cosf(ang); st[t2] = sinf(ang);
  }
}

// ---------------------------------------------------------------- GEMM1: c_q/c_kv = x @ W1 (tile 128x256)
__global__ __launch_bounds__(512, 2) void k_gemm1(const float* __restrict__ X,
    const unsigned short* __restrict__ Bt, unsigned short* __restrict__ Cq,
    unsigned short* __restrict__ Ckv) {
  __shared__ __align__(16) unsigned short Ash[128 * 72];
  __shared__ __align__(16) unsigned short Bsh[256 * 72];
  const int nt2 = blockIdx.x, mt = blockIdx.y;
  const int tid = threadIdx.x;
  const int l = tid & 63, wv = tid >> 6, li = l & 15, g = l >> 4;
  const int wm = wv >> 2, wn = wv & 3;
  const f32x4 zf = {0.f, 0.f, 0.f, 0.f};
  f32x4 acc[4][4];
#pragma unroll
  for (int i = 0; i < 4; ++i)
#pragma unroll
    for (int j = 0; j < 4; ++j) acc[i][j] = zf;
  for (int kb = 0; kb < 256; kb += 64) {
    __syncthreads();
#pragma unroll
    for (int it = 0; it < 4; ++it) {        // A: 128x64 f32 -> bf16
      int idx = it * 512 + tid;
      int row = idx >> 4, c4 = (idx & 15) << 2;
      f32x4 v = *reinterpret_cast<const f32x4*>(X + (size_t)(mt * 128 + row) * 256 + kb + c4);
      u16x4 u = { f2b(v.x), f2b(v.y), f2b(v.z), f2b(v.w) };
      *reinterpret_cast<u16x4*>(&Ash[row * 72 + c4]) = u;
    }
#pragma unroll
    for (int it = 0; it < 4; ++it) {        // B: 256 rows of W1t
      int idx = it * 512 + tid;
      int row = idx >> 3, c8 = (idx & 7) << 3;
      *reinterpret_cast<u16x8*>(&Bsh[row * 72 + c8]) =
        *reinterpret_cast<const u16x8*>(Bt + (size_t)(nt2 * 256 + row) * 256 + kb + c8);
    }
    __syncthreads();
#pragma unroll
    for (int kc = 0; kc < 2; ++kc) {
      bf16x8 a[4], b[4];
#pragma unroll
      for (int mf = 0; mf < 4; ++mf)
        a[mf] = *reinterpret_cast<const bf16x8*>(&Ash[(wm * 64 + mf * 16 + li) * 72 + kc * 32 + g * 8]);
#pragma unroll
      for (int nf = 0; nf < 4; ++nf)
        b[nf] = *reinterpret_cast<const bf16x8*>(&Bsh[(wn * 64 + nf * 16 + li) * 72 + kc * 32 + g * 8]);
#pragma unroll
      for (int mf = 0; mf < 4; ++mf)
#pragma unroll
        for (int nf = 0; nf < 4; ++nf)
          acc[mf][nf] = mfma16(a[mf], b[nf], acc[mf][nf]);
    }
  }
  unsigned short* C = nt2 ? Ckv : Cq;
#pragma unroll
  for (int mf = 0; mf < 4; ++mf)
#pragma unroll
    for (int nf = 0; nf < 4; ++nf)
#pragma unroll
      for (int r = 0; r < 4; ++r) {
        int row = mt * 128 + wm * 64 + mf * 16 + g * 4 + r;
        int col = wn * 64 + nf * 16 + li;
        C[(size_t)row * 256 + col] = f2b(acc[mf][nf][r]);
      }
}

// ---------------------------------------------------------------- GEMM2: q/k/v projections (+RoPE, +vt transpose)
__global__ __launch_bounds__(512, 2) void k_gemm2(const unsigned short* __restrict__ Cq,
    const unsigned short* __restrict__ Ckv,
    const unsigned short* __restrict__ Wqt, const unsigned short* __restrict__ Wkvt,
    unsigned short* __restrict__ q_ws, unsigned short* __restrict__ k_ws,
    float* __restrict__ kout, float* __restrict__ vout,
    unsigned short* __restrict__ vt,
    const float* __restrict__ ct, const float* __restrict__ st, int sel0) {
  __shared__ __align__(16) unsigned short Ash[128 * 72];
  __shared__ __align__(16) unsigned short Bsh[256 * 72];
  const int sel = sel0 + blockIdx.x, mt = blockIdx.y;   // 0=q 1=k 2=v
  const int tid = threadIdx.x;
  const int l = tid & 63, wv = tid >> 6, li = l & 15, g = l >> 4;
  const int wm = wv >> 2, wn = wv & 3;
  const unsigned short* Asrc = (sel == 0) ? Cq : Ckv;
  const unsigned short* Wt = (sel == 0) ? Wqt : Wkvt;
  const int wrow = (sel == 2) ? 256 : 0;
  const f32x4 zf = {0.f, 0.f, 0.f, 0.f};
  f32x4 acc[4][4];
#pragma unroll
  for (int i = 0; i < 4; ++i)
#pragma unroll
    for (int j = 0; j < 4; ++j) acc[i][j] = zf;
  for (int kb = 0; kb < 256; kb += 64) {
    __syncthreads();
#pragma unroll
    for (int it = 0; it < 2; ++it) {        // A: 128x64 bf16
      int idx = it * 512 + tid;
      int row = idx >> 3, c8 = (idx & 7) << 3;
      *reinterpret_cast<u16x8*>(&Ash[row * 72 + c8]) =
        *reinterpret_cast<const u16x8*>(Asrc + (size_t)(mt * 128 + row) * 256 + kb + c8);
    }
#pragma unroll
    for (int it = 0; it < 4; ++it) {        // B: 256 rows
      int idx = it * 512 + tid;
      int row = idx >> 3, c8 = (idx & 7) << 3;
      *reinterpret_cast<u16x8*>(&Bsh[row * 72 + c8]) =
        *reinterpret_cast<const u16x8*>(Wt + (size_t)(wrow + row) * 256 + kb + c8);
    }
    __syncthreads();
#pragma unroll
    for (int kc = 0; kc < 2; ++kc) {
      bf16x8 a[4], b[4];
#pragma unroll
      for (int mf = 0; mf < 4; ++mf)
        a[mf] = *reinterpret_cast<const bf16x8*>(&Ash[(wm * 64 + mf * 16 + li) * 72 + kc * 32 + g * 8]);
#pragma unroll
      for (int nf = 0; nf < 4; ++nf)
        b[nf] = *reinterpret_cast<const bf16x8*>(&Bsh[(wn * 64 + nf * 16 + li) * 72 + kc * 32 + g * 8]);
#pragma unroll
      for (int mf = 0; mf < 4; ++mf)
#pragma unroll
        for (int nf = 0; nf < 4; ++nf)
          acc[mf][nf] = mfma16(a[mf], b[nf], acc[mf][nf]);
    }
  }
  // fused RoPE on local cols 192..255 (wn==3) for q (sel 0) and k (sel 1)
  if (sel < 2 && wn == 3) {
#pragma unroll
    for (int mf = 0; mf < 4; ++mf)
#pragma unroll
      for (int nf = 0; nf < 4; ++nf)
#pragma unroll
        for (int r = 0; r < 4; ++r) {
          float v = acc[mf][nf][r];
          float other = __shfl_xor(v, 1);
          int t = (mt * 128 + wm * 64 + mf * 16 + g * 4 + r) & 2047;
          int i = nf * 8 + (li >> 1);
          float c = ct[t * 32 + i], s = st[t * 32 + i];
          acc[mf][nf][r] = (li & 1) ? (other * s + v * c) : (v * c - other * s);
        }
  }
#pragma unroll
  for (int mf = 0; mf < 4; ++mf)
#pragma unroll
    for (int nf = 0; nf < 4; ++nf) {
      int cl = wn * 64 + nf * 16 + li;     // 0..255
#pragma unroll
      for (int r = 0; r < 4; ++r) {
        int row = mt * 128 + wm * 64 + mf * 16 + g * 4 + r;
        float val = acc[mf][nf][r];
        if (sel == 0) {
          q_ws[(size_t)row * 256 + cl] = f2b(val);
        } else if (sel == 1) {
          k_ws[(size_t)row * 256 + cl] = f2b(val);
          kout[(size_t)row * 256 + cl] = val;
        } else {
          vout[(size_t)row * 256 + cl] = val;
        }
      }
    }
  // sel==2: transposed bf16 write of this 128x256 tile into vt[b][d][t] via LDS bounce
  if (sel == 2) {
    const int batch = mt >> 4, tbase = (mt & 15) * 128;
#pragma unroll
    for (int h = 0; h < 2; ++h) {
      __syncthreads();
      if (wm == h) {
#pragma unroll
        for (int mf = 0; mf < 4; ++mf)
#pragma unroll
          for (int nf = 0; nf < 4; ++nf)
#pragma unroll
            for (int r = 0; r < 4; ++r) {
              int lr = mf * 16 + g * 4 + r;                  // 0..63
              int col = wn * 64 + nf * 16 + li;
              Bsh[lr * 258 + col] = f2b(acc[mf][nf][r]);
            }
      }
      __syncthreads();
#pragma unroll
      for (int it2 = 0; it2 < 8; ++it2) {
        int idx = it2 * 512 + tid;
        int d = idx >> 4, tq = (idx & 15) << 2;
        u16x4 pk = { Bsh[(tq + 0) * 258 + d], Bsh[(tq + 1) * 258 + d],
                     Bsh[(tq + 2) * 258 + d], Bsh[(tq + 3) * 258 + d] };
        *reinterpret_cast<u16x4*>(vt + ((size_t)batch * 256 + d) * 2048 + tbase + h * 64 + tq) = pk;
      }
    }
  }
}

// ---------------------------------------------------------------- flash attention (exact R3 body, 136us verified)
// grid(32 batches, 8 pairs): wgid = b + 32*p -> batch b pinned to XCD b%8 (L2 reuse).
// 512 thr = 8 waves; Q-tile 128, wave wv owns rows [wv*16, wv*16+16), full D=256.
// Fixed max softmax P = exp(s/16 - 8); row sum via ones-MFMA; reg-staged dbuf.
__global__ __launch_bounds__(512, 2) void k_attn(
    const unsigned short* __restrict__ q_ws, const unsigned short* __restrict__ k_ws,
    const unsigned short* __restrict__ vt_ws, float* __restrict__ out) {
  __shared__ __align__(16) unsigned short Ksh[64 * 256];   // [kr][d] chunk-swizzled (32KB)
  __shared__ __align__(16) unsigned short Vsh[256 * 64];   // [d][kk] chunk-swizzled (32KB)
  __shared__ __align__(16) unsigned short Psh[8][1024];    // per-wave [16 q][64 kk] swizzled (16KB)
  const int b = blockIdx.x;        // batch -> XCD affinity
  const int p = blockIdx.y;        // causal pair index 0..7
  const int tid = threadIdx.x;
  const int l = tid & 63, wv = tid >> 6, li = l & 15, g = l >> 4;
  const f32x4 zf = {0.f, 0.f, 0.f, 0.f};

  u16x8 ones_u = {0x3F80, 0x3F80, 0x3F80, 0x3F80, 0x3F80, 0x3F80, 0x3F80, 0x3F80};
  bf16x8 ones = *reinterpret_cast<bf16x8*>(&ones_u);

  const int s_kr = tid >> 5, s_kc = tid & 31;   // K stage: rows s_kr+16*it
  const int s_kpc = s_kc ^ (s_kr & 7);
  const int s_vd = tid >> 3, s_vc = tid & 7;    // V stage: d rows s_vd+64*it
  const int s_vpc = s_vc ^ (s_vd & 7);

  const unsigned short* kbase = k_ws + (size_t)b * 2048 * 256;
  const unsigned short* vbase = vt_ws + (size_t)b * 256 * 2048;

  u16x8 kreg[4], vreg[4];

  for (int seg = 0; seg < 2; ++seg) {
    const int qt = seg ? (15 - p) : p;
    const int wq0 = qt * 128 + wv * 16;
    bf16x8 qf[8];
    const unsigned short* qp = q_ws + ((size_t)b * 2048 + wq0 + li) * 256;
#pragma unroll
    for (int kc = 0; kc < 8; ++kc)
      qf[kc] = *reinterpret_cast<const bf16x8*>(qp + kc * 32 + g * 8);

    f32x4 o[16];
#pragma unroll
    for (int i = 0; i < 16; ++i) o[i] = zf;
    f32x4 ol = zf;

    const int nj = 2 * qt + 2;
    // prologue loads for j=0
#pragma unroll
    for (int it = 0; it < 4; ++it)
      kreg[it] = *reinterpret_cast<const u16x8*>(kbase + (size_t)(s_kr + it * 16) * 256 + s_kc * 8);
#pragma unroll
    for (int it = 0; it < 4; ++it)
      vreg[it] = *reinterpret_cast<const u16x8*>(vbase + (size_t)(s_vd + it * 64) * 2048 + s_vc * 8);

    for (int j = 0; j < nj; ++j) {
      __syncthreads();                       // prev-iteration readers done
#pragma unroll
      for (int it = 0; it < 4; ++it)
        *reinterpret_cast<u16x8*>(&Ksh[(s_kr + it * 16) * 256 + s_kpc * 8]) = kreg[it];
#pragma unroll
      for (int it = 0; it < 4; ++it)
        *reinterpret_cast<u16x8*>(&Vsh[(s_vd + it * 64) * 64 + s_vpc * 8]) = vreg[it];
      __syncthreads();
      if (j + 1 < nj) {                      // T14: prefetch next tile into regs
        const unsigned short* kb2 = kbase + (size_t)(j + 1) * 64 * 256;
        const unsigned short* vb2 = vbase + (size_t)(j + 1) * 64;
#pragma unroll
        for (int it = 0; it < 4; ++it)
          kreg[it] = *reinterpret_cast<const u16x8*>(kb2 + (size_t)(s_kr + it * 16) * 256 + s_kc * 8);
#pragma unroll
        for (int it = 0; it < 4; ++it)
          vreg[it] = *reinterpret_cast<const u16x8*>(vb2 + (size_t)(s_vd + it * 64) * 2048 + s_vc * 8);
      }
      if (j * 64 > qt * 128 + wv * 16 + 15) continue;   // wave fully masked

      // QK^T: 16 q rows x 64 k rows
      f32x4 s[4];
#pragma unroll
      for (int nf = 0; nf < 4; ++nf) s[nf] = zf;
#pragma unroll
      for (int kc = 0; kc < 8; ++kc) {
        int pc = (kc * 4 + g) ^ (li & 7);
#pragma unroll
        for (int nf = 0; nf < 4; ++nf) {
          bf16x8 bk = *reinterpret_cast<const bf16x8*>(&Ksh[(nf * 16 + li) * 256 + pc * 8]);
          s[nf] = mfma16(qf[kc], bk, s[nf]);
        }
      }
      // fixed-max numerator, causal mask, pack P to per-wave LDS
#pragma unroll
      for (int r = 0; r < 4; ++r) {
        const int q = g * 4 + r;
        const int qg = wv * 16 + q;          // q row relative to qt*128
#pragma unroll
        for (int nf = 0; nf < 4; ++nf) {
          int kg = j * 64 + nf * 16 + li - qt * 128;   // <=0 for non-diag tiles
          float pv = __expf(__builtin_fmaf(s[nf][r], 0.0625f, -8.0f));
          if (kg > qg) pv = 0.f;
          int kk = nf * 16 + li;
          int pcp = (kk >> 3) ^ (q & 7);
          Psh[wv][q * 64 + pcp * 8 + (kk & 7)] = f2b(pv);
        }
      }
      // PV: O += P @ V ; l += P @ ones (per-wave P, no barrier needed)
#pragma unroll
      for (int kc2 = 0; kc2 < 2; ++kc2) {
        int pcp = (kc2 * 4 + g) ^ (li & 7);
        bf16x8 pa = *reinterpret_cast<const bf16x8*>(&Psh[wv][li * 64 + pcp * 8]);
        ol = mfma16(pa, ones, ol);
#pragma unroll
        for (int nfd = 0; nfd < 16; ++nfd) {
          bf16x8 bv = *reinterpret_cast<const bf16x8*>(&Vsh[(nfd * 16 + li) * 64 + pcp * 8]);
          o[nfd] = mfma16(pa, bv, o[nfd]);
        }
      }
    }

    // epilogue: 16 rows x 256 cols
#pragma unroll
    for (int r = 0; r < 4; ++r) {
      float inv = 1.0f / ol[r];
      int qrow = wq0 + g * 4 + r;
      float* op = out + ((size_t)b * 2048 + qrow) * 256;
#pragma unroll
      for (int nfd = 0; nfd < 16; ++nfd)
        op[nfd * 16 + li] = o[nfd][r] * inv;
    }
  }
}

// ---------------------------------------------------------------- launch
extern "C" void kernel_launch(void* const* d_in, const int* in_sizes, int n_in,
                              void* d_out, int out_size, void* d_ws, size_t ws_size,
                              hipStream_t stream) {
  const float* x        = (const float*)d_in[0];
  const float* Wq_comp  = (const float*)d_in[1];
  const float* Wkv_comp = (const float*)d_in[2];
  const float* Wqc      = (const float*)d_in[3];
  const float* Wqr      = (const float*)d_in[4];
  const float* Wkc      = (const float*)d_in[5];
  const float* Wkr      = (const float*)d_in[6];
  const float* Wv       = (const float*)d_in[7];

  float* out  = (float*)d_out;            // [32][2048][256]
  float* kout = out + 16777216;           // k output (f32)
  float* vout = out + 33554432;           // v output (f32)

  if (ws_size < 135397376u) return;

  char* ws = (char*)d_ws;
  unsigned short* c_q  = (unsigned short*)(ws);              // 32MB (vt aliases after q done)
  unsigned short* vt   = (unsigned short*)(ws);              // [32][256][2048] bf16 (32MB)
  unsigned short* c_kv = (unsigned short*)(ws + 33554432);   // 32MB
  unsigned short* q_ws = (unsigned short*)(ws + 67108864);   // 32MB
  unsigned short* k_ws = (unsigned short*)(ws + 100663296);  // 32MB
  unsigned short* W1t  = (unsigned short*)(ws + 134217728);  // 512x256
  unsigned short* Wqt  = W1t + 131072;                       // 256x256
  unsigned short* Wkvt = Wqt + 65536;                        // 512x256
  float* ct = (float*)(Wkvt + 131072);                       // 2048x32
  float* st = ct + 65536;

  k_prep<<<1536, 256, 0, stream>>>(Wq_comp, Wkv_comp, Wqc, Wqr, Wkc, Wkr, Wv,
                                   W1t, Wqt, Wkvt, ct, st);
  k_gemm1<<<dim3(2, 512), 512, 0, stream>>>(x, W1t, c_q, c_kv);
  // q and k first (read c_q/c_kv); then v (reads only c_kv, writes vt over c_q)
  k_gemm2<<<dim3(2, 512), 512, 0, stream>>>(c_q, c_kv, Wqt, Wkvt, q_ws, k_ws,
                                            kout, vout, vt, ct, st, 0);
  k_gemm2<<<dim3(1, 512), 512, 0, stream>>>(c_q, c_kv, Wqt, Wkvt, q_ws, k_ws,
                                            kout, vout, vt, ct, st, 2);
  k_attn<<<dim3(32, 8), 512, 0, stream>>>(q_ws, k_ws, vt, out);
}

// Round 12
// 257.314 us; speedup vs baseline: 2.3076x; 1.0242x over previous
//
#include <hip/hip_runtime.h>

typedef float  f32x4  __attribute__((ext_vector_type(4)));
typedef __bf16 bf16x8 __attribute__((ext_vector_type(8)));
typedef unsigned short u16x8 __attribute__((ext_vector_type(8)));
typedef unsigned short u16x4 __attribute__((ext_vector_type(4)));

#define DEV static __device__ __forceinline__

DEV unsigned short f2b(float f) {            // f32 -> bf16 (RNE)
  unsigned int u = __float_as_uint(f);
  u += 0x7fffu + ((u >> 16) & 1u);
  return (unsigned short)(u >> 16);
}
DEV float b2f(unsigned short h) { return __uint_as_float(((unsigned int)h) << 16); }

DEV f32x4 mfma16(bf16x8 a, bf16x8 b, f32x4 c) {
  return __builtin_amdgcn_mfma_f32_16x16x32_bf16(a, b, c, 0, 0, 0);
}

// ---------------------------------------------------------------- prep
__global__ __launch_bounds__(256) void k_prep(
    const float* __restrict__ Wq_comp, const float* __restrict__ Wkv_comp,
    const float* __restrict__ Wqc, const float* __restrict__ Wqr,
    const float* __restrict__ Wkc, const float* __restrict__ Wkr,
    const float* __restrict__ Wv,
    unsigned short* __restrict__ W1t, unsigned short* __restrict__ Wqt,
    unsigned short* __restrict__ Wkvt, float* __restrict__ ct, float* __restrict__ st) {
  int tid = blockIdx.x * 256 + threadIdx.x;
  if (tid < 131072) {                       // W1t
    int n = tid >> 8, k = tid & 255;
    float v = (n < 256) ? Wq_comp[k * 256 + n] : Wkv_comp[k * 256 + (n - 256)];
    W1t[tid] = f2b(v);
  } else if (tid < 196608) {                // Wqt
    int t2 = tid - 131072; int n = t2 >> 8, k = t2 & 255;
    float v = (n < 192) ? Wqc[k * 192 + n] : Wqr[k * 64 + (n - 192)];
    Wqt[t2] = f2b(v);
  } else if (tid < 327680) {                // Wkvt
    int t2 = tid - 196608; int n = t2 >> 8, k = t2 & 255;
    float v = (n < 192) ? Wkc[k * 192 + n]
             : (n < 256) ? Wkr[k * 64 + (n - 192)] : Wv[k * 256 + (n - 256)];
    Wkvt[t2] = f2b(v);
  } else if (tid < 393216) {                // rope table
    int t2 = tid - 327680; int t = t2 >> 5, i = t2 & 31;
    float theta = powf(10000.0f, -(float)i / 32.0f);
    float ang = (float)t * theta;
    ct[t2] = cosf(ang); st[t2] = sinf(ang);
  }
}

// ---------------------------------------------------------------- GEMM1: c_q/c_kv = x @ W1 (tile 128x256)
__global__ __launch_bounds__(512, 2) void k_gemm1(const float* __restrict__ X,
    const unsigned short* __restrict__ Bt, unsigned short* __restrict__ Cq,
    unsigned short* __restrict__ Ckv) {
  __shared__ __align__(16) unsigned short Ash[128 * 72];
  __shared__ __align__(16) unsigned short Bsh[256 * 72];
  const int nt2 = blockIdx.x, mt = blockIdx.y;
  const int tid = threadIdx.x;
  const int l = tid & 63, wv = tid >> 6, li = l & 15, g = l >> 4;
  const int wm = wv >> 2, wn = wv & 3;
  const f32x4 zf = {0.f, 0.f, 0.f, 0.f};
  f32x4 acc[4][4];
#pragma unroll
  for (int i = 0; i < 4; ++i)
#pragma unroll
    for (int j = 0; j < 4; ++j) acc[i][j] = zf;
  for (int kb = 0; kb < 256; kb += 64) {
    __syncthreads();
#pragma unroll
    for (int it = 0; it < 4; ++it) {        // A: 128x64 f32 -> bf16
      int idx = it * 512 + tid;
      int row = idx >> 4, c4 = (idx & 15) << 2;
      f32x4 v = *reinterpret_cast<const f32x4*>(X + (size_t)(mt * 128 + row) * 256 + kb + c4);
      u16x4 u = { f2b(v.x), f2b(v.y), f2b(v.z), f2b(v.w) };
      *reinterpret_cast<u16x4*>(&Ash[row * 72 + c4]) = u;
    }
#pragma unroll
    for (int it = 0; it < 4; ++it) {        // B: 256 rows of W1t
      int idx = it * 512 + tid;
      int row = idx >> 3, c8 = (idx & 7) << 3;
      *reinterpret_cast<u16x8*>(&Bsh[row * 72 + c8]) =
        *reinterpret_cast<const u16x8*>(Bt + (size_t)(nt2 * 256 + row) * 256 + kb + c8);
    }
    __syncthreads();
#pragma unroll
    for (int kc = 0; kc < 2; ++kc) {
      bf16x8 a[4], b[4];
#pragma unroll
      for (int mf = 0; mf < 4; ++mf)
        a[mf] = *reinterpret_cast<const bf16x8*>(&Ash[(wm * 64 + mf * 16 + li) * 72 + kc * 32 + g * 8]);
#pragma unroll
      for (int nf = 0; nf < 4; ++nf)
        b[nf] = *reinterpret_cast<const bf16x8*>(&Bsh[(wn * 64 + nf * 16 + li) * 72 + kc * 32 + g * 8]);
#pragma unroll
      for (int mf = 0; mf < 4; ++mf)
#pragma unroll
        for (int nf = 0; nf < 4; ++nf)
          acc[mf][nf] = mfma16(a[mf], b[nf], acc[mf][nf]);
    }
  }
  unsigned short* C = nt2 ? Ckv : Cq;
#pragma unroll
  for (int mf = 0; mf < 4; ++mf)
#pragma unroll
    for (int nf = 0; nf < 4; ++nf)
#pragma unroll
      for (int r = 0; r < 4; ++r) {
        int row = mt * 128 + wm * 64 + mf * 16 + g * 4 + r;
        int col = wn * 64 + nf * 16 + li;
        C[(size_t)row * 256 + col] = f2b(acc[mf][nf][r]);
      }
}

// ---------------------------------------------------------------- GEMM2: q/k/v projections (+RoPE, +vt transpose)
__global__ __launch_bounds__(512, 2) void k_gemm2(const unsigned short* __restrict__ Cq,
    const unsigned short* __restrict__ Ckv,
    const unsigned short* __restrict__ Wqt, const unsigned short* __restrict__ Wkvt,
    unsigned short* __restrict__ q_ws, unsigned short* __restrict__ k_ws,
    float* __restrict__ kout, float* __restrict__ vout,
    unsigned short* __restrict__ vt,
    const float* __restrict__ ct, const float* __restrict__ st, int sel0) {
  __shared__ __align__(16) unsigned short Ash[128 * 72];
  __shared__ __align__(16) unsigned short Bsh[256 * 72];
  const int sel = sel0 + blockIdx.x, mt = blockIdx.y;   // 0=q 1=k 2=v
  const int tid = threadIdx.x;
  const int l = tid & 63, wv = tid >> 6, li = l & 15, g = l >> 4;
  const int wm = wv >> 2, wn = wv & 3;
  const unsigned short* Asrc = (sel == 0) ? Cq : Ckv;
  const unsigned short* Wt = (sel == 0) ? Wqt : Wkvt;
  const int wrow = (sel == 2) ? 256 : 0;
  const f32x4 zf = {0.f, 0.f, 0.f, 0.f};
  f32x4 acc[4][4];
#pragma unroll
  for (int i = 0; i < 4; ++i)
#pragma unroll
    for (int j = 0; j < 4; ++j) acc[i][j] = zf;
  for (int kb = 0; kb < 256; kb += 64) {
    __syncthreads();
#pragma unroll
    for (int it = 0; it < 2; ++it) {        // A: 128x64 bf16
      int idx = it * 512 + tid;
      int row = idx >> 3, c8 = (idx & 7) << 3;
      *reinterpret_cast<u16x8*>(&Ash[row * 72 + c8]) =
        *reinterpret_cast<const u16x8*>(Asrc + (size_t)(mt * 128 + row) * 256 + kb + c8);
    }
#pragma unroll
    for (int it = 0; it < 4; ++it) {        // B: 256 rows
      int idx = it * 512 + tid;
      int row = idx >> 3, c8 = (idx & 7) << 3;
      *reinterpret_cast<u16x8*>(&Bsh[row * 72 + c8]) =
        *reinterpret_cast<const u16x8*>(Wt + (size_t)(wrow + row) * 256 + kb + c8);
    }
    __syncthreads();
#pragma unroll
    for (int kc = 0; kc < 2; ++kc) {
      bf16x8 a[4], b[4];
#pragma unroll
      for (int mf = 0; mf < 4; ++mf)
        a[mf] = *reinterpret_cast<const bf16x8*>(&Ash[(wm * 64 + mf * 16 + li) * 72 + kc * 32 + g * 8]);
#pragma unroll
      for (int nf = 0; nf < 4; ++nf)
        b[nf] = *reinterpret_cast<const bf16x8*>(&Bsh[(wn * 64 + nf * 16 + li) * 72 + kc * 32 + g * 8]);
#pragma unroll
      for (int mf = 0; mf < 4; ++mf)
#pragma unroll
        for (int nf = 0; nf < 4; ++nf)
          acc[mf][nf] = mfma16(a[mf], b[nf], acc[mf][nf]);
    }
  }
  // fused RoPE on local cols 192..255 (wn==3) for q (sel 0) and k (sel 1)
  if (sel < 2 && wn == 3) {
#pragma unroll
    for (int mf = 0; mf < 4; ++mf)
#pragma unroll
      for (int nf = 0; nf < 4; ++nf)
#pragma unroll
        for (int r = 0; r < 4; ++r) {
          float v = acc[mf][nf][r];
          float other = __shfl_xor(v, 1);
          int t = (mt * 128 + wm * 64 + mf * 16 + g * 4 + r) & 2047;
          int i = nf * 8 + (li >> 1);
          float c = ct[t * 32 + i], s = st[t * 32 + i];
          acc[mf][nf][r] = (li & 1) ? (other * s + v * c) : (v * c - other * s);
        }
  }
#pragma unroll
  for (int mf = 0; mf < 4; ++mf)
#pragma unroll
    for (int nf = 0; nf < 4; ++nf) {
      int cl = wn * 64 + nf * 16 + li;     // 0..255
#pragma unroll
      for (int r = 0; r < 4; ++r) {
        int row = mt * 128 + wm * 64 + mf * 16 + g * 4 + r;
        float val = acc[mf][nf][r];
        if (sel == 0) {
          q_ws[(size_t)row * 256 + cl] = f2b(val);
        } else if (sel == 1) {
          k_ws[(size_t)row * 256 + cl] = f2b(val);
          kout[(size_t)row * 256 + cl] = val;
        } else {
          vout[(size_t)row * 256 + cl] = val;
        }
      }
    }
  // sel==2: transposed bf16 write of this 128x256 tile into vt[b][d][t] via LDS bounce
  if (sel == 2) {
    const int batch = mt >> 4, tbase = (mt & 15) * 128;
#pragma unroll
    for (int h = 0; h < 2; ++h) {
      __syncthreads();
      if (wm == h) {
#pragma unroll
        for (int mf = 0; mf < 4; ++mf)
#pragma unroll
          for (int nf = 0; nf < 4; ++nf)
#pragma unroll
            for (int r = 0; r < 4; ++r) {
              int lr = mf * 16 + g * 4 + r;                  // 0..63
              int col = wn * 64 + nf * 16 + li;
              Bsh[lr * 258 + col] = f2b(acc[mf][nf][r]);
            }
      }
      __syncthreads();
#pragma unroll
      for (int it2 = 0; it2 < 8; ++it2) {
        int idx = it2 * 512 + tid;
        int d = idx >> 4, tq = (idx & 15) << 2;
        u16x4 pk = { Bsh[(tq + 0) * 258 + d], Bsh[(tq + 1) * 258 + d],
                     Bsh[(tq + 2) * 258 + d], Bsh[(tq + 3) * 258 + d] };
        *reinterpret_cast<u16x4*>(vt + ((size_t)batch * 256 + d) * 2048 + tbase + h * 64 + tq) = pk;
      }
    }
  }
}

// ---------------------------------------------------------------- flash attention v11 (R3 body + wave-pair V-sharing)
// 512 thr = 8 waves = 4 pairs. Pair wp covers q rows [qt*128+wp*32, +32); within a
// pair, wave wd owns 16 rows for QK^T/softmax and d-half [wd*128, +128) for PV.
// PV reads BOTH pair P buffers per V fragment -> V LDS reads halved (each bv feeds
// 2 MFMAs). Pair activity is uniform (no divergent barriers). P handoff uses an
// lgkm-only s_barrier (vmcnt prefetch stays in flight). Everything else == R3.
__global__ __launch_bounds__(512, 2) void k_attn(
    const unsigned short* __restrict__ q_ws, const unsigned short* __restrict__ k_ws,
    const unsigned short* __restrict__ vt_ws, float* __restrict__ out) {
  __shared__ __align__(16) unsigned short Ksh[64 * 256];   // [kr][d] chunk-swizzled (32KB)
  __shared__ __align__(16) unsigned short Vsh[256 * 64];   // [d][kk] chunk-swizzled (32KB)
  __shared__ __align__(16) unsigned short Psh[8][1024];    // per-wave [16 q][64 kk] swizzled (16KB)
  const int b = blockIdx.x;        // batch -> XCD affinity
  const int p = blockIdx.y;        // causal pair index 0..7
  const int tid = threadIdx.x;
  const int l = tid & 63, wv = tid >> 6, li = l & 15, g = l >> 4;
  const int wp = wv >> 1, wd = wv & 1;   // pair index, d-half
  const f32x4 zf = {0.f, 0.f, 0.f, 0.f};

  u16x8 ones_u = {0x3F80, 0x3F80, 0x3F80, 0x3F80, 0x3F80, 0x3F80, 0x3F80, 0x3F80};
  bf16x8 ones = *reinterpret_cast<bf16x8*>(&ones_u);

  const int s_kr = tid >> 5, s_kc = tid & 31;   // K stage: rows s_kr+16*it
  const int s_kpc = s_kc ^ (s_kr & 7);
  const int s_vd = tid >> 3, s_vc = tid & 7;    // V stage: d rows s_vd+64*it
  const int s_vpc = s_vc ^ (s_vd & 7);

  const unsigned short* kbase = k_ws + (size_t)b * 2048 * 256;
  const unsigned short* vbase = vt_ws + (size_t)b * 256 * 2048;

  u16x8 kreg[4], vreg[4];

  for (int seg = 0; seg < 2; ++seg) {
    const int qt = seg ? (15 - p) : p;
    const int rowbase = qt * 128 + wp * 32;     // pair's 32 rows
    const int own0 = rowbase + wd * 16;         // this wave's 16 rows (QK/softmax)
    bf16x8 qf[8];
    const unsigned short* qp = q_ws + ((size_t)b * 2048 + own0 + li) * 256;
#pragma unroll
    for (int kc = 0; kc < 8; ++kc)
      qf[kc] = *reinterpret_cast<const bf16x8*>(qp + kc * 32 + g * 8);

    f32x4 o[2][8];                              // [pair row-group][own d-half nfd]
#pragma unroll
    for (int i = 0; i < 2; ++i)
#pragma unroll
      for (int j2 = 0; j2 < 8; ++j2) o[i][j2] = zf;
    f32x4 ol[2] = {zf, zf};

    const int nj = 2 * qt + 2;
    // prologue loads for j=0
#pragma unroll
    for (int it = 0; it < 4; ++it)
      kreg[it] = *reinterpret_cast<const u16x8*>(kbase + (size_t)(s_kr + it * 16) * 256 + s_kc * 8);
#pragma unroll
    for (int it = 0; it < 4; ++it)
      vreg[it] = *reinterpret_cast<const u16x8*>(vbase + (size_t)(s_vd + it * 64) * 2048 + s_vc * 8);

    for (int j = 0; j < nj; ++j) {
      __syncthreads();                       // prev-iteration readers done
#pragma unroll
      for (int it = 0; it < 4; ++it)
        *reinterpret_cast<u16x8*>(&Ksh[(s_kr + it * 16) * 256 + s_kpc * 8]) = kreg[it];
#pragma unroll
      for (int it = 0; it < 4; ++it)
        *reinterpret_cast<u16x8*>(&Vsh[(s_vd + it * 64) * 64 + s_vpc * 8]) = vreg[it];
      __syncthreads();
      if (j + 1 < nj) {                      // prefetch next tile into regs
        const unsigned short* kb2 = kbase + (size_t)(j + 1) * 64 * 256;
        const unsigned short* vb2 = vbase + (size_t)(j + 1) * 64;
#pragma unroll
        for (int it = 0; it < 4; ++it)
          kreg[it] = *reinterpret_cast<const u16x8*>(kb2 + (size_t)(s_kr + it * 16) * 256 + s_kc * 8);
#pragma unroll
        for (int it = 0; it < 4; ++it)
          vreg[it] = *reinterpret_cast<const u16x8*>(vb2 + (size_t)(s_vd + it * 64) * 2048 + s_vc * 8);
      }
      const bool active = (j * 64 <= rowbase + 31);   // pair-uniform activity

      if (active) {
        // QK^T: own 16 q rows x 64 k rows
        f32x4 s[4];
#pragma unroll
        for (int nf = 0; nf < 4; ++nf) s[nf] = zf;
#pragma unroll
        for (int kc = 0; kc < 8; ++kc) {
          int pc = (kc * 4 + g) ^ (li & 7);
#pragma unroll
          for (int nf = 0; nf < 4; ++nf) {
            bf16x8 bk = *reinterpret_cast<const bf16x8*>(&Ksh[(nf * 16 + li) * 256 + pc * 8]);
            s[nf] = mfma16(qf[kc], bk, s[nf]);
          }
        }
        // fixed-max numerator, causal mask, pack P to per-wave LDS
#pragma unroll
        for (int r = 0; r < 4; ++r) {
          const int q = g * 4 + r;
          const int qg = wp * 32 + wd * 16 + q;        // row relative to qt*128
#pragma unroll
          for (int nf = 0; nf < 4; ++nf) {
            int kg = j * 64 + nf * 16 + li - qt * 128; // <=0 for non-diag tiles
            float pv = __expf(__builtin_fmaf(s[nf][r], 0.0625f, -8.0f));
            if (kg > qg) pv = 0.f;
            int kk = nf * 16 + li;
            int pcp = (kk >> 3) ^ (q & 7);
            Psh[wv][q * 64 + pcp * 8 + (kk & 7)] = f2b(pv);
          }
        }
      }
      // P handoff within pair: lgkm-only barrier (keep vmcnt prefetch in flight)
      asm volatile("s_waitcnt lgkmcnt(0)\n\ts_barrier" ::: "memory");
      __builtin_amdgcn_sched_barrier(0);

      if (active) {
        // PV: O[both row groups][own d-half] += P @ V ; each bv feeds 2 MFMAs
#pragma unroll
        for (int kc2 = 0; kc2 < 2; ++kc2) {
          int pcp = (kc2 * 4 + g) ^ (li & 7);
          bf16x8 pa0 = *reinterpret_cast<const bf16x8*>(&Psh[wp * 2 + 0][li * 64 + pcp * 8]);
          bf16x8 pa1 = *reinterpret_cast<const bf16x8*>(&Psh[wp * 2 + 1][li * 64 + pcp * 8]);
          ol[0] = mfma16(pa0, ones, ol[0]);
          ol[1] = mfma16(pa1, ones, ol[1]);
#pragma unroll
          for (int nfd = 0; nfd < 8; ++nfd) {
            int d = wd * 128 + nfd * 16 + li;
            bf16x8 bv = *reinterpret_cast<const bf16x8*>(&Vsh[d * 64 + pcp * 8]);
            o[0][nfd] = mfma16(pa0, bv, o[0][nfd]);
            o[1][nfd] = mfma16(pa1, bv, o[1][nfd]);
          }
        }
      }
    }

    // epilogue: 32 pair rows x own 128-col d-half
#pragma unroll
    for (int mf = 0; mf < 2; ++mf)
#pragma unroll
      for (int r = 0; r < 4; ++r) {
        float inv = 1.0f / ol[mf][r];
        int qrow = rowbase + mf * 16 + g * 4 + r;
        float* op = out + ((size_t)b * 2048 + qrow) * 256 + wd * 128;
#pragma unroll
        for (int nfd = 0; nfd < 8; ++nfd)
          op[nfd * 16 + li] = o[mf][nfd][r] * inv;
      }
  }
}

// ---------------------------------------------------------------- launch
extern "C" void kernel_launch(void* const* d_in, const int* in_sizes, int n_in,
                              void* d_out, int out_size, void* d_ws, size_t ws_size,
                              hipStream_t stream) {
  const float* x        = (const float*)d_in[0];
  const float* Wq_comp  = (const float*)d_in[1];
  const float* Wkv_comp = (const float*)d_in[2];
  const float* Wqc      = (const float*)d_in[3];
  const float* Wqr      = (const float*)d_in[4];
  const float* Wkc      = (const float*)d_in[5];
  const float* Wkr      = (const float*)d_in[6];
  const float* Wv       = (const float*)d_in[7];

  float* out  = (float*)d_out;            // [32][2048][256]
  float* kout = out + 16777216;           // k output (f32)
  float* vout = out + 33554432;           // v output (f32)

  if (ws_size < 135397376u) return;

  char* ws = (char*)d_ws;
  unsigned short* c_q  = (unsigned short*)(ws);              // 32MB (vt aliases after q done)
  unsigned short* vt   = (unsigned short*)(ws);              // [32][256][2048] bf16 (32MB)
  unsigned short* c_kv = (unsigned short*)(ws + 33554432);   // 32MB
  unsigned short* q_ws = (unsigned short*)(ws + 67108864);   // 32MB
  unsigned short* k_ws = (unsigned short*)(ws + 100663296);  // 32MB
  unsigned short* W1t  = (unsigned short*)(ws + 134217728);  // 512x256
  unsigned short* Wqt  = W1t + 131072;                       // 256x256
  unsigned short* Wkvt = Wqt + 65536;                        // 512x256
  float* ct = (float*)(Wkvt + 131072);                       // 2048x32
  float* st = ct + 65536;

  k_prep<<<1536, 256, 0, stream>>>(Wq_comp, Wkv_comp, Wqc, Wqr, Wkc, Wkr, Wv,
                                   W1t, Wqt, Wkvt, ct, st);
  k_gemm1<<<dim3(2, 512), 512, 0, stream>>>(x, W1t, c_q, c_kv);
  // q and k first (read c_q/c_kv); then v (reads only c_kv, writes vt over c_q)
  k_gemm2<<<dim3(2, 512), 512, 0, stream>>>(c_q, c_kv, Wqt, Wkvt, q_ws, k_ws,
                                            kout, vout, vt, ct, st, 0);
  k_gemm2<<<dim3(1, 512), 512, 0, stream>>>(c_q, c_kv, Wqt, Wkvt, q_ws, k_ws,
                                            kout, vout, vt, ct, st, 2);
  k_attn<<<dim3(32, 8), 512, 0, stream>>>(q_ws, k_ws, vt, out);
}